// Round 12
// baseline (621.551 us; speedup 1.0000x reference)
//
#include <hip/hip_runtime.h>
#include <stdint.h>

#define B_ 16
#define S_ 64
#define M_ 4096
#define D_ 1024
#define H_ 16
#define DH_ 64

typedef unsigned short ushort_t;
typedef __attribute__((ext_vector_type(8))) __bf16 bfrag;   // 8 bf16 = 4 VGPRs
typedef __attribute__((ext_vector_type(4))) float f32x4;
typedef __attribute__((ext_vector_type(4))) uint32_t u32x4;

// fp32 -> bf16 RNE
__device__ __forceinline__ ushort_t f2bf(float f) {
  union { float f; uint32_t u; } v; v.f = f;
  uint32_t r = v.u + 0x7fffu + ((v.u >> 16) & 1u);
  return (ushort_t)(r >> 16);
}

__device__ __forceinline__ void gload_lds16(const void* g, void* l) {
  __builtin_amdgcn_global_load_lds((const __attribute__((address_space(1))) void*)g,
                                   (__attribute__((address_space(3))) void*)l, 16, 0, 0);
}

// inline-asm LDS read: invisible to compiler DMA-alias tracking (no implicit
// vmcnt drains before the read cluster). Caller fences with lgkmcnt(0) +
// sched_barrier(0) before consuming (rule #18). Proven correct in R8.
__device__ __forceinline__ bfrag ds_read128(const ushort_t* p) {
  u32x4 r;
  uint32_t a = (uint32_t)(uintptr_t)(const __attribute__((address_space(3))) ushort_t*)p;
  asm volatile("ds_read_b128 %0, %1" : "=v"(r) : "v"(a));
  union { u32x4 u; bfrag b; } c;
  c.u = r;
  return c.b;
}

__device__ __forceinline__ f32x4 mfma16x16x32(bfrag a, bfrag b, f32x4 c) {
  return __builtin_amdgcn_mfma_f32_16x16x32_bf16(a, b, c, 0, 0, 0);
}

// epilogue-region swizzle: granule ^= fsw(row); fsw>>1 injective over klo groups
__device__ __forceinline__ int fsw(int r) { return (((r >> 2) & 3) << 1) | (r & 1); }

// ---------------- LayerNorm rows (1024 wide) -> bf16 ----------------
__global__ __launch_bounds__(256) void ln_rows_kernel(
    const float* __restrict__ x, const float* __restrict__ g,
    const float* __restrict__ bta, ushort_t* __restrict__ out) {
  const int row = blockIdx.x;
  const int t = threadIdx.x;
  const float4* xr = (const float4*)(x + (size_t)row * D_);
  float4 v = xr[t];
  float s = v.x + v.y + v.z + v.w;
  float ss = v.x * v.x + v.y * v.y + v.z * v.z + v.w * v.w;
#pragma unroll
  for (int o = 32; o >= 1; o >>= 1) { s += __shfl_down(s, o); ss += __shfl_down(ss, o); }
  __shared__ float red[16];
  const int wid = t >> 6;
  if ((t & 63) == 0) { red[wid] = s; red[8 + wid] = ss; }
  __syncthreads();
  float tot = red[0] + red[1] + red[2] + red[3];
  float tot2 = red[8] + red[9] + red[10] + red[11];
  float mu = tot * (1.0f / D_);
  float var = tot2 * (1.0f / D_) - mu * mu;
  float rstd = rsqrtf(var + 1e-5f);
  float4 gg = ((const float4*)g)[t];
  float4 bb = ((const float4*)bta)[t];
  ushort_t ob[4];
  ob[0] = f2bf((v.x - mu) * rstd * gg.x + bb.x);
  ob[1] = f2bf((v.y - mu) * rstd * gg.y + bb.y);
  ob[2] = f2bf((v.z - mu) * rstd * gg.z + bb.z);
  ob[3] = f2bf((v.w - mu) * rstd * gg.w + bb.w);
  *(uint2*)(out + (size_t)row * D_ + t * 4) = *(const uint2*)ob;
}

// ---------------- W[K=1024][N] fp32 -> WT[N][1024] bf16 (scaled) ----------------
__global__ void transpose_cast_kernel(const float* __restrict__ W, ushort_t* __restrict__ WT,
                                      int N, float scale) {
  __shared__ float tile[32][33];
  const int n0 = blockIdx.x * 32, k0 = blockIdx.y * 32;
  const int tx = threadIdx.x, ty = threadIdx.y;
#pragma unroll
  for (int i = ty; i < 32; i += 8)
    tile[i][tx] = W[(size_t)(k0 + i) * N + n0 + tx];
  __syncthreads();
#pragma unroll
  for (int i = ty; i < 32; i += 8)
    WT[(size_t)(n0 + i) * D_ + k0 + tx] = f2bf(tile[tx][i] * scale);
}

// ---------------- kv GEMM (small, 4.3 GF): 128x128, scatter to (b,h,s,d) ----------
__global__ __launch_bounds__(256) void gemm_kv_kernel(
    const ushort_t* __restrict__ A, const ushort_t* __restrict__ Bt,
    ushort_t* __restrict__ kb, ushort_t* __restrict__ vb) {
  __shared__ __align__(16) ushort_t sA[128 * 32];
  __shared__ __align__(16) ushort_t sB[128 * 32];
  const int tid = threadIdx.x, wid = tid >> 6, lane = tid & 63;
  const size_t arow0 = (size_t)blockIdx.x * 128;
  const size_t brow0 = (size_t)blockIdx.y * 128;
  const int wr = (wid >> 1) * 64, wc = (wid & 1) * 64;
  const int srow = tid >> 2, scol = (tid & 3) * 8;
  const ushort_t* ga = A + (arow0 + srow) * (size_t)D_ + scol;
  const ushort_t* gb = Bt + (brow0 + srow) * (size_t)D_ + scol;
  const int frow = lane & 15, kslot = (lane >> 4) * 8;
  f32x4 acc[4][4] = {};
  for (int k0 = 0; k0 < D_; k0 += 32) {
    gload_lds16(ga, sA + wid * 512);
    gload_lds16(ga + 64 * (size_t)D_, sA + 2048 + wid * 512);
    gload_lds16(gb, sB + wid * 512);
    gload_lds16(gb + 64 * (size_t)D_, sB + 2048 + wid * 512);
    ga += 32; gb += 32;
    __syncthreads();
    bfrag af[4], bfv[4];
#pragma unroll
    for (int m = 0; m < 4; ++m)
      af[m] = *(const bfrag*)&sA[(wr + m * 16 + frow) * 32 + kslot];
#pragma unroll
    for (int n = 0; n < 4; ++n)
      bfv[n] = *(const bfrag*)&sB[(wc + n * 16 + frow) * 32 + kslot];
#pragma unroll
    for (int m = 0; m < 4; ++m)
#pragma unroll
      for (int n = 0; n < 4; ++n)
        acc[m][n] = mfma16x16x32(af[m], bfv[n], acc[m][n]);
    __syncthreads();
  }
  const int erow = (lane >> 4) * 4, ecol = lane & 15;
#pragma unroll
  for (int m = 0; m < 4; ++m)
#pragma unroll
    for (int n = 0; n < 4; ++n)
#pragma unroll
      for (int r = 0; r < 4; ++r) {
        size_t i = arow0 + wr + m * 16 + erow + r;
        int bb = (int)(i >> 6), s = (int)(i & 63);
        size_t n2 = brow0 + wc + n * 16 + ecol;
        ushort_t val = f2bf(acc[m][n][r]);
        ushort_t* dst = (n2 < 1024) ? kb : vb;
        size_t hh = (n2 & 1023) >> 6, d = n2 & 63;
        dst[(((size_t)bb * H_ + hh) * S_ + s) * DH_ + d] = val;
      }
}

// ====== 256x256 GEMM, BK=64 period (16 barriers), B direct from L2, A-only LDS =====
// R11's BK=64 raced (2-slot ring: STAGE wrote the slot being read). Race-free
// form: A ring = 4 ghalf-slots x 16KB; period t reads slots {2t&3,(2t+1)&3};
// STAGE_A(t+1) (after the barrier) writes the COMPLEMENTARY pair, whose readers
// (period t-1) all passed the barrier. B never enters LDS: the 2MB weight panel
// is L2-resident (chunked XCD map), read as per-lane global dwordx4 frags —
// halves LDS pipe traffic and staging. vmcnt(0) at period top waits only on
// loads issued a full period ago (free in steady state). A reads via asm
// ds_read_b128 + lgkmcnt(0) + sched_barrier (R8-proven, rule #18); then 64
// MFMA back-to-back under setprio.
// MODE 0: epilogue = fp32 C store; MODE 1: fused attention per wave-half.
template <int MODE>
__global__ __launch_bounds__(512, 2) void gemm256_kernel(
    const ushort_t* __restrict__ A, const ushort_t* __restrict__ Bt,
    const ushort_t* __restrict__ kbuf, const ushort_t* __restrict__ vbuf,
    void* __restrict__ Cout) {
  __shared__ __align__(16) ushort_t lds[32768];  // 64KB: A ring, 4 x [256][32]
  const int tid = threadIdx.x, wid = tid >> 6, lane = tid & 63;
  const int frow = lane & 15, klo = lane >> 4;
  const int wm = wid >> 2, wn = wid & 3;

  // XCD-swizzled block mapping (1024 = 8*128, bijective)
  const int l = ((int)blockIdx.x & 7) * 128 + ((int)blockIdx.x >> 3);
  const int mblk = l >> 2, nblk = l & 3;
  const size_t arow0 = (size_t)mblk * 256;
  const size_t bcol0 = (size_t)nblk * 256;

  // A staging: thread covers rows r0, r0+128 at stored granule tid&3, which
  // holds source granule (tid&3)^((r0>>1)&3)  [LDS dst linear, m173 pattern]
  const int r0 = tid >> 2;
  const int gsrc = (tid & 3) ^ ((tid >> 3) & 3);
  const ushort_t* pA = A + (arow0 + r0) * (size_t)D_ + gsrc * 8;
  // A frag read: swizzled granule offset (rows 16-aligned: (row>>1)&3 == (frow>>1)&3)
  const int rasw = (klo ^ ((frow >> 1) & 3)) * 8;
  // B direct-read row base (per-lane): row = bcol0 + wn*64 + nf*16 + frow
  const ushort_t* pBrow = Bt + (bcol0 + (size_t)(wn * 64 + frow)) * (size_t)D_ + klo * 8;

  // STAGE_A(T): ghalves 2T, 2T+1 (K cols T*64..T*64+64) -> slots (2T)&3, (2T+1)&3.
  // Slot parity from UNCLAMPED g; tail (T=16) lands garbage in slots 0,1 (drained).
#define STAGE_A(T)                                                            \
  do {                                                                        \
    _Pragma("unroll") for (int sub = 0; sub < 2; ++sub) {                     \
      const int g_ = 2 * (T) + sub;                                           \
      const size_t ko_ = (size_t)(g_ < 32 ? g_ : 31) * 32;                    \
      const int sb_ = (g_ & 3) * 8192;                                        \
      gload_lds16(pA + ko_, &lds[sb_ + wid * 512]);                           \
      gload_lds16(pA + 128 * (size_t)D_ + ko_, &lds[sb_ + 4096 + wid * 512]); \
    }                                                                         \
  } while (0)

  // prologue: period 0's A (4 loads/thread)
  STAGE_A(0);

  f32x4 acc[8][4] = {};
  for (int t = 0; t < 16; ++t) {
    // loads outstanding here were issued one full period ago -> near-free wait
    asm volatile("s_waitcnt vmcnt(0)" ::: "memory");
    __builtin_amdgcn_s_barrier();
    asm volatile("" ::: "memory");
    // B frags for this period: L2-resident weight panel, per-lane gathers.
    // Issued BEFORE STAGE_A so the compiler's pre-MFMA vmcnt wait for them
    // leaves the (younger) A-stage DMA in flight.
    bfrag bf[4][2];
#pragma unroll
    for (int nf = 0; nf < 4; ++nf)
#pragma unroll
      for (int kk = 0; kk < 2; ++kk)
        bf[nf][kk] = *(const bfrag*)&pBrow[(size_t)nf * 16 * D_ + t * 64 + kk * 32];
    // stage period t+1's A into the complementary slot pair (race-free)
    STAGE_A(t + 1);
    // A frag reads, both K-halves (asm; no compiler alias drains)
    const int s0 = ((2 * t) & 3) * 8192;
    const int s1 = ((2 * t + 1) & 3) * 8192;
    bfrag a0[8], a1[8];
#pragma unroll
    for (int mf = 0; mf < 8; ++mf) {
      const int ro = (wm * 128 + mf * 16 + frow) * 32 + rasw;
      a0[mf] = ds_read128(&lds[s0 + ro]);
      a1[mf] = ds_read128(&lds[s1 + ro]);
    }
    asm volatile("s_waitcnt lgkmcnt(0)" ::: "memory");
    __builtin_amdgcn_sched_barrier(0);
    __builtin_amdgcn_s_setprio(1);
#pragma unroll
    for (int mf = 0; mf < 8; ++mf)
#pragma unroll
      for (int nf = 0; nf < 4; ++nf)
        acc[mf][nf] = mfma16x16x32(a0[mf], bf[nf][0], acc[mf][nf]);
#pragma unroll
    for (int mf = 0; mf < 8; ++mf)
#pragma unroll
      for (int nf = 0; nf < 4; ++nf)
        acc[mf][nf] = mfma16x16x32(a1[mf], bf[nf][1], acc[mf][nf]);
    __builtin_amdgcn_s_setprio(0);
    __builtin_amdgcn_sched_barrier(0);  // keep MFMAs in-phase
  }
  // drain tail garbage-stages before reusing LDS / exiting
  asm volatile("s_waitcnt vmcnt(0)" ::: "memory");
  __builtin_amdgcn_s_barrier();
  __builtin_amdgcn_sched_barrier(0);
#undef STAGE_A

  if constexpr (MODE == 0) {
    // ---------------- epilogue: fp32 C store (acc[m] rows = m*16 + klo*4 + r) -----
    float* C = (float*)Cout;
#pragma unroll
    for (int m = 0; m < 8; ++m)
#pragma unroll
      for (int n = 0; n < 4; ++n)
#pragma unroll
        for (int r = 0; r < 4; ++r)
          C[(arow0 + wm * 128 + m * 16 + klo * 4 + r) * 1024 + bcol0 + wn * 64 + n * 16 + frow] =
              acc[m][n][r];
  } else {
    // ---------------- epilogue: fused attention (wave-private) ----------------
    ushort_t* W = &lds[wid * 4096];  // [64][64] bf16, granule ^= fsw(row); ring is dead
    ushort_t* out1 = (ushort_t*)Cout;
    const int head = nblk * 4 + wn;
    const int bbatch = mblk >> 4;
    const size_t kvbase = ((size_t)bbatch * H_ + head) * (size_t)(S_ * DH_);
    bfrag kb[4][2], vb[4][2];
#pragma unroll
    for (int nf = 0; nf < 4; ++nf)
#pragma unroll
      for (int kk = 0; kk < 2; ++kk) {
        kb[nf][kk] = *(const bfrag*)&kbuf[kvbase + (nf * 16 + frow) * 64 + kk * 32 + klo * 8];
        vb[nf][kk] = *(const bfrag*)&vbuf[kvbase + (nf * 16 + frow) * 64 + kk * 32 + klo * 8];
      }
#pragma unroll
    for (int hh = 0; hh < 2; ++hh) {
      // q -> W (bf16, swizzled)
#pragma unroll
      for (int m2 = 0; m2 < 4; ++m2)
#pragma unroll
        for (int r = 0; r < 4; ++r) {
          const int row = m2 * 16 + klo * 4 + r;
          const int fs = fsw(row);
#pragma unroll
          for (int n = 0; n < 4; ++n) {
            const int cc = n * 16 + frow;
            W[row * 64 + ((((cc >> 3) ^ fs) << 3) | (cc & 7))] = f2bf(acc[hh * 4 + m2][n][r]);
          }
        }
      // sim = q @ K^T
      f32x4 s[4][4] = {};
#pragma unroll
      for (int m2 = 0; m2 < 4; ++m2) {
        const int row = m2 * 16 + frow;
        const int fs = fsw(row);
#pragma unroll
        for (int kk = 0; kk < 2; ++kk) {
          bfrag qa = *(const bfrag*)&W[row * 64 + (((kk * 4 + klo) ^ fs) << 3)];
#pragma unroll
          for (int nf = 0; nf < 4; ++nf)
            s[m2][nf] = mfma16x16x32(qa, kb[nf][kk], s[m2][nf]);
        }
      }
      // softmax over 64 keys (row in one 16-lane group, 4 keys/lane/frag)
#pragma unroll
      for (int m2 = 0; m2 < 4; ++m2)
#pragma unroll
        for (int r = 0; r < 4; ++r) {
          float a0 = s[m2][0][r], a1 = s[m2][1][r], a2 = s[m2][2][r], a3 = s[m2][3][r];
          float mx = fmaxf(fmaxf(a0, a1), fmaxf(a2, a3));
#pragma unroll
          for (int o = 1; o < 16; o <<= 1) mx = fmaxf(mx, __shfl_xor(mx, o));
          a0 = __expf(a0 - mx); a1 = __expf(a1 - mx);
          a2 = __expf(a2 - mx); a3 = __expf(a3 - mx);
          float sm = (a0 + a1) + (a2 + a3);
#pragma unroll
          for (int o = 1; o < 16; o <<= 1) sm += __shfl_xor(sm, o);
          const float inv = 1.0f / sm;
          s[m2][0][r] = a0 * inv; s[m2][1][r] = a1 * inv;
          s[m2][2][r] = a2 * inv; s[m2][3][r] = a3 * inv;
        }
      // P -> W (overwrite q; wave-private, in-order LDS)
#pragma unroll
      for (int m2 = 0; m2 < 4; ++m2)
#pragma unroll
        for (int r = 0; r < 4; ++r) {
          const int row = m2 * 16 + klo * 4 + r;
          const int fs = fsw(row);
#pragma unroll
          for (int n = 0; n < 4; ++n) {
            const int cc = n * 16 + frow;
            W[row * 64 + ((((cc >> 3) ^ fs) << 3) | (cc & 7))] = f2bf(s[m2][n][r]);
          }
        }
      // out1_half = attn @ "V^T" (einsum quirk: contract attn-keys with V dims)
      f32x4 o[4][4] = {};
#pragma unroll
      for (int m2 = 0; m2 < 4; ++m2) {
        const int row = m2 * 16 + frow;
        const int fs = fsw(row);
#pragma unroll
        for (int kk = 0; kk < 2; ++kk) {
          bfrag pa = *(const bfrag*)&W[row * 64 + (((kk * 4 + klo) ^ fs) << 3)];
#pragma unroll
          for (int nf = 0; nf < 4; ++nf)
            o[m2][nf] = mfma16x16x32(pa, vb[nf][kk], o[m2][nf]);
        }
      }
      // o -> W then coalesced uint4 stores
#pragma unroll
      for (int m2 = 0; m2 < 4; ++m2)
#pragma unroll
        for (int r = 0; r < 4; ++r) {
          const int row = m2 * 16 + klo * 4 + r;
          const int fs = fsw(row);
#pragma unroll
          for (int n = 0; n < 4; ++n) {
            const int cc = n * 16 + frow;
            W[row * 64 + ((((cc >> 3) ^ fs) << 3) | (cc & 7))] = f2bf(o[m2][n][r]);
          }
        }
      const size_t grow0 = arow0 + wm * 128 + hh * 64;
#pragma unroll
      for (int it = 0; it < 8; ++it) {
        const int idx = it * 64 + lane;
        const int rr = idx >> 3, gs = idx & 7;
        const int gcol = (gs ^ fsw(rr)) << 3;
        *(uint4*)&out1[(grow0 + rr) * 1024 + head * 64 + gcol] =
            *(const uint4*)&W[rr * 64 + gs * 8];
      }
    }
  }
}

// -------------------------------- launch --------------------------------
extern "C" void kernel_launch(void* const* d_in, const int* in_sizes, int n_in,
                              void* d_out, int out_size, void* d_ws, size_t ws_size,
                              hipStream_t stream) {
  const float* x = (const float*)d_in[0];
  const float* lat = (const float*)d_in[1];
  const float* lxg = (const float*)d_in[2];
  const float* lxb = (const float*)d_in[3];
  const float* llg = (const float*)d_in[4];
  const float* llb = (const float*)d_in[5];
  const float* Wq = (const float*)d_in[6];
  const float* Wkv = (const float*)d_in[7];
  const float* Wout = (const float*)d_in[8];
  float* out = (float*)d_out;
  char* ws = (char*)d_ws;

  // ws layout (142MB): xn 2MB | wqT 2MB | wkvT 4MB | woT 2MB | k 2MB | v 2MB | out1 128MB
  ushort_t* xn = (ushort_t*)(ws);
  ushort_t* wqT = (ushort_t*)(ws + (2ull << 20));
  ushort_t* wkvT = (ushort_t*)(ws + (4ull << 20));
  ushort_t* woT = (ushort_t*)(ws + (8ull << 20));
  ushort_t* kbuf = (ushort_t*)(ws + (10ull << 20));
  ushort_t* vbuf = (ushort_t*)(ws + (12ull << 20));
  ushort_t* out1 = (ushort_t*)(ws + (14ull << 20));
  // lnl (bf16, 128MB) lives in d_out's first half: dead before final GEMM writes d_out
  ushort_t* lnl = (ushort_t*)d_out;

  dim3 tb(32, 8);
  transpose_cast_kernel<<<dim3(1024 / 32, 32), tb, 0, stream>>>(Wq, wqT, 1024, 0.125f);
  transpose_cast_kernel<<<dim3(2048 / 32, 32), tb, 0, stream>>>(Wkv, wkvT, 2048, 1.0f);
  transpose_cast_kernel<<<dim3(1024 / 32, 32), tb, 0, stream>>>(Wout, woT, 1024, 1.0f);
  ln_rows_kernel<<<B_ * S_, 256, 0, stream>>>(x, lxg, lxb, xn);
  ln_rows_kernel<<<B_ * M_, 256, 0, stream>>>(lat, llg, llb, lnl);
  gemm_kv_kernel<<<dim3(8, 16), 256, 0, stream>>>(xn, wkvT, kbuf, vbuf);
  gemm256_kernel<1><<<1024, 512, 0, stream>>>(lnl, wqT, kbuf, vbuf, out1);
  gemm256_kernel<0><<<1024, 512, 0, stream>>>(out1, woT, nullptr, nullptr, out);
}

// Round 13
// 463.028 us; speedup vs baseline: 1.3424x; 1.3424x over previous
//
#include <hip/hip_runtime.h>
#include <stdint.h>

#define B_ 16
#define S_ 64
#define M_ 4096
#define D_ 1024
#define H_ 16
#define DH_ 64

typedef unsigned short ushort_t;
typedef __attribute__((ext_vector_type(8))) __bf16 bfrag;   // 8 bf16 = 4 VGPRs
typedef __attribute__((ext_vector_type(4))) float f32x4;

// fp32 -> bf16 RNE
__device__ __forceinline__ ushort_t f2bf(float f) {
  union { float f; uint32_t u; } v; v.f = f;
  uint32_t r = v.u + 0x7fffu + ((v.u >> 16) & 1u);
  return (ushort_t)(r >> 16);
}

__device__ __forceinline__ void gload_lds16(const void* g, void* l) {
  __builtin_amdgcn_global_load_lds((const __attribute__((address_space(1))) void*)g,
                                   (__attribute__((address_space(3))) void*)l, 16, 0, 0);
}

__device__ __forceinline__ f32x4 mfma16x16x32(bfrag a, bfrag b, f32x4 c) {
  return __builtin_amdgcn_mfma_f32_16x16x32_bf16(a, b, c, 0, 0, 0);
}

// epilogue-region swizzle: granule ^= fsw(row); fsw>>1 injective over klo groups
__device__ __forceinline__ int fsw(int r) { return (((r >> 2) & 3) << 1) | (r & 1); }

// ---------------- LayerNorm: ONE WAVE PER ROW (no LDS, no barriers) ----------------
// 4 rows per 256-thread block; per lane 4x float4 (64B), 6-step shuffle reduce.
__global__ __launch_bounds__(256) void ln_rows_kernel(
    const float* __restrict__ x, const float* __restrict__ g,
    const float* __restrict__ bta, ushort_t* __restrict__ out) {
  const int wrow = blockIdx.x * 4 + (threadIdx.x >> 6);
  const int lane = threadIdx.x & 63;
  const float4* xr = (const float4*)(x + (size_t)wrow * D_);
  float4 v[4];
  float s = 0.0f, ss = 0.0f;
#pragma unroll
  for (int j = 0; j < 4; ++j) {
    v[j] = xr[j * 64 + lane];
    s += (v[j].x + v[j].y) + (v[j].z + v[j].w);
    ss += (v[j].x * v[j].x + v[j].y * v[j].y) + (v[j].z * v[j].z + v[j].w * v[j].w);
  }
#pragma unroll
  for (int o = 32; o >= 1; o >>= 1) { s += __shfl_down(s, o); ss += __shfl_down(ss, o); }
  s = __shfl(s, 0);
  ss = __shfl(ss, 0);
  const float mu = s * (1.0f / D_);
  const float var = ss * (1.0f / D_) - mu * mu;
  const float rstd = rsqrtf(var + 1e-5f);
  ushort_t* orow = out + (size_t)wrow * D_;
#pragma unroll
  for (int j = 0; j < 4; ++j) {
    const float4 gg = ((const float4*)g)[j * 64 + lane];
    const float4 bb = ((const float4*)bta)[j * 64 + lane];
    ushort_t ob[4];
    ob[0] = f2bf((v[j].x - mu) * rstd * gg.x + bb.x);
    ob[1] = f2bf((v[j].y - mu) * rstd * gg.y + bb.y);
    ob[2] = f2bf((v[j].z - mu) * rstd * gg.z + bb.z);
    ob[3] = f2bf((v[j].w - mu) * rstd * gg.w + bb.w);
    *(uint2*)(orow + (size_t)(j * 64 + lane) * 4) = *(const uint2*)ob;
  }
}

// ---------------- W[K=1024][N] fp32 -> WT[N][1024] bf16 (scaled) ----------------
__global__ void transpose_cast_kernel(const float* __restrict__ W, ushort_t* __restrict__ WT,
                                      int N, float scale) {
  __shared__ float tile[32][33];
  const int n0 = blockIdx.x * 32, k0 = blockIdx.y * 32;
  const int tx = threadIdx.x, ty = threadIdx.y;
#pragma unroll
  for (int i = ty; i < 32; i += 8)
    tile[i][tx] = W[(size_t)(k0 + i) * N + n0 + tx];
  __syncthreads();
#pragma unroll
  for (int i = ty; i < 32; i += 8)
    WT[(size_t)(n0 + i) * D_ + k0 + tx] = f2bf(tile[tx][i] * scale);
}

// ---------------- kv GEMM (small, 4.3 GF): 128x128, scatter to (b,h,s,d) ----------
__global__ __launch_bounds__(256) void gemm_kv_kernel(
    const ushort_t* __restrict__ A, const ushort_t* __restrict__ Bt,
    ushort_t* __restrict__ kb, ushort_t* __restrict__ vb) {
  __shared__ __align__(16) ushort_t sA[128 * 32];
  __shared__ __align__(16) ushort_t sB[128 * 32];
  const int tid = threadIdx.x, wid = tid >> 6, lane = tid & 63;
  const size_t arow0 = (size_t)blockIdx.x * 128;
  const size_t brow0 = (size_t)blockIdx.y * 128;
  const int wr = (wid >> 1) * 64, wc = (wid & 1) * 64;
  const int srow = tid >> 2, scol = (tid & 3) * 8;
  const ushort_t* ga = A + (arow0 + srow) * (size_t)D_ + scol;
  const ushort_t* gb = Bt + (brow0 + srow) * (size_t)D_ + scol;
  const int frow = lane & 15, kslot = (lane >> 4) * 8;
  f32x4 acc[4][4] = {};
  for (int k0 = 0; k0 < D_; k0 += 32) {
    gload_lds16(ga, sA + wid * 512);
    gload_lds16(ga + 64 * (size_t)D_, sA + 2048 + wid * 512);
    gload_lds16(gb, sB + wid * 512);
    gload_lds16(gb + 64 * (size_t)D_, sB + 2048 + wid * 512);
    ga += 32; gb += 32;
    __syncthreads();
    bfrag af[4], bfv[4];
#pragma unroll
    for (int m = 0; m < 4; ++m)
      af[m] = *(const bfrag*)&sA[(wr + m * 16 + frow) * 32 + kslot];
#pragma unroll
    for (int n = 0; n < 4; ++n)
      bfv[n] = *(const bfrag*)&sB[(wc + n * 16 + frow) * 32 + kslot];
#pragma unroll
    for (int m = 0; m < 4; ++m)
#pragma unroll
      for (int n = 0; n < 4; ++n)
        acc[m][n] = mfma16x16x32(af[m], bfv[n], acc[m][n]);
    __syncthreads();
  }
  const int erow = (lane >> 4) * 4, ecol = lane & 15;
#pragma unroll
  for (int m = 0; m < 4; ++m)
#pragma unroll
    for (int n = 0; n < 4; ++n)
#pragma unroll
      for (int r = 0; r < 4; ++r) {
        size_t i = arow0 + wr + m * 16 + erow + r;
        int bb = (int)(i >> 6), s = (int)(i & 63);
        size_t n2 = brow0 + wc + n * 16 + ecol;
        ushort_t val = f2bf(acc[m][n][r]);
        ushort_t* dst = (n2 < 1024) ? kb : vb;
        size_t hh = (n2 & 1023) >> 6, d = n2 & 63;
        dst[(((size_t)bb * H_ + hh) * S_ + s) * DH_ + d] = val;
      }
}

// ============== 256x256 read-ahead-pipelined GEMM, C = A * Bt^T (R6, best) ========
// ghalf g = K cols [g*32, g*32+32), 16KB slot; 4-slot ring/operand (128KB LDS).
// 8 waves (2m x 4n), per-wave 128x64 out. 2 phases per ghalf, ONE barrier each.
// REGISTER READ-AHEAD: phase p's MFMA consumes frags ds_read during phase p-1,
// so post-barrier lgkmcnt(0) drains reads issued a full phase earlier.
// vmcnt(6) once per ghalf. Stage lead = 3 ghalfs (ring distance covers WAR).
// MODE 0: epilogue = fp32 C store; MODE 1: fused attention per wave-half.
template <int MODE>
__global__ __launch_bounds__(512, 2) void gemm256_kernel(
    const ushort_t* __restrict__ A, const ushort_t* __restrict__ Bt,
    const ushort_t* __restrict__ kbuf, const ushort_t* __restrict__ vbuf,
    void* __restrict__ Cout) {
  __shared__ __align__(16) ushort_t lds[65536];  // 128KB: A ring 64KB | B ring 64KB
  const int tid = threadIdx.x, wid = tid >> 6, lane = tid & 63;
  const int frow = lane & 15, klo = lane >> 4;
  const int wm = wid >> 2, wn = wid & 3;

  // XCD-swizzled block mapping (1024 = 8*128, bijective)
  const int l = ((int)blockIdx.x & 7) * 128 + ((int)blockIdx.x >> 3);
  const int mblk = l >> 2, nblk = l & 3;
  const size_t arow0 = (size_t)mblk * 256;
  const size_t bcol0 = (size_t)nblk * 256;

  // staging: thread covers (row, gidx) = (tid>>2, tid&3)
  // stored granule gidx holds source granule gidx ^ ((row>>1)&3)
  const int r0 = tid >> 2;
  const int gsrc = (tid & 3) ^ ((tid >> 3) & 3);
  const ushort_t* pA0 = A + (arow0 + r0) * (size_t)D_ + gsrc * 8;
  const ushort_t* pA1 = pA0 + (size_t)128 * D_;
  const ushort_t* pB0 = Bt + (bcol0 + r0) * (size_t)D_ + gsrc * 8;
  const ushort_t* pB1 = pB0 + (size_t)128 * D_;
  // ds_read swizzled granule offset (constant per lane)
  const int rasw = (klo ^ ((frow >> 1) & 3)) * 8;

#define STAGE_A(G)                                                            \
  do {                                                                        \
    const int s_ = (G) & 3;                                                   \
    const size_t ko_ = (size_t)((G) < 32 ? (G) : 31) * 32;                    \
    gload_lds16(pA0 + ko_, &lds[s_ * 8192 + wid * 512]);                      \
    gload_lds16(pA1 + ko_, &lds[s_ * 8192 + 4096 + wid * 512]);               \
  } while (0)
#define STAGE_B(G)                                                            \
  do {                                                                        \
    const int s_ = (G) & 3;                                                   \
    const size_t ko_ = (size_t)((G) < 32 ? (G) : 31) * 32;                    \
    gload_lds16(pB0 + ko_, &lds[32768 + s_ * 8192 + wid * 512]);              \
    gload_lds16(pB1 + ko_, &lds[32768 + s_ * 8192 + 4096 + wid * 512]);       \
  } while (0)

  // prologue: ghalfs 0,1,2 staged; first 4 loads (A0,B0) verified; read phase-0 frags
  STAGE_A(0); STAGE_B(0);
  STAGE_A(1); STAGE_B(1);
  STAGE_A(2); STAGE_B(2);
  asm volatile("s_waitcnt vmcnt(8)" ::: "memory");
  __builtin_amdgcn_s_barrier();
  bfrag aC[4], aN[4], bC[4], bN[4];
  {
    const ushort_t* As = &lds[0];
    const ushort_t* Bs = &lds[32768];
#pragma unroll
    for (int mf = 0; mf < 4; ++mf)
      aC[mf] = *(const bfrag*)&As[(wm * 128 + mf * 16 + frow) * 32 + rasw];
#pragma unroll
    for (int nf = 0; nf < 4; ++nf)
      bC[nf] = *(const bfrag*)&Bs[(wn * 64 + nf * 16 + frow) * 32 + rasw];
  }

  f32x4 acc[8][4] = {};
  for (int g = 0; g < 32; ++g) {
    // ---------------- phase 0 (mh=0): MFMA(aC,bC); read-ahead aN = A(g,mh1) -------
    __builtin_amdgcn_s_barrier();
    asm volatile("s_waitcnt lgkmcnt(0)" ::: "memory");
    __builtin_amdgcn_sched_barrier(0);
    __builtin_amdgcn_s_setprio(1);
    {
      const ushort_t* As = &lds[(g & 3) * 8192];
#pragma unroll
      for (int mf = 0; mf < 4; ++mf) {
#pragma unroll
        for (int nf = 0; nf < 4; ++nf)
          acc[mf][nf] = mfma16x16x32(aC[mf], bC[nf], acc[mf][nf]);
        aN[mf] = *(const bfrag*)&As[(wm * 128 + 64 + mf * 16 + frow) * 32 + rasw];
      }
    }
    __builtin_amdgcn_s_setprio(0);
    STAGE_A(g + 3);
    // ---------------- phase 1 (mh=1): MFMA(aN,bC); read-ahead aC,bN = {A,B}(g+1) --
    asm volatile("s_waitcnt vmcnt(6)" ::: "memory");
    __builtin_amdgcn_s_barrier();
    asm volatile("s_waitcnt lgkmcnt(0)" ::: "memory");
    __builtin_amdgcn_sched_barrier(0);
    __builtin_amdgcn_s_setprio(1);
    {
      const int gn = (g + 1 < 32) ? g + 1 : 31;
      const ushort_t* As2 = &lds[(gn & 3) * 8192];
      const ushort_t* Bs2 = &lds[32768 + (gn & 3) * 8192];
#pragma unroll
      for (int mf = 0; mf < 4; ++mf) {
#pragma unroll
        for (int nf = 0; nf < 4; ++nf)
          acc[4 + mf][nf] = mfma16x16x32(aN[mf], bC[nf], acc[4 + mf][nf]);
        aC[mf] = *(const bfrag*)&As2[(wm * 128 + mf * 16 + frow) * 32 + rasw];
        bN[mf] = *(const bfrag*)&Bs2[(wn * 64 + mf * 16 + frow) * 32 + rasw];
      }
    }
    __builtin_amdgcn_s_setprio(0);
    STAGE_B(g + 3);
#pragma unroll
    for (int nf = 0; nf < 4; ++nf) bC[nf] = bN[nf];
  }
  // drain tail stages before reusing LDS / exiting
  asm volatile("s_waitcnt vmcnt(0)" ::: "memory");
  __builtin_amdgcn_s_barrier();
  __builtin_amdgcn_sched_barrier(0);
#undef STAGE_A
#undef STAGE_B

  if constexpr (MODE == 0) {
    // ---------------- epilogue: fp32 C store (acc[m] rows = m*16 + klo*4 + r) -----
    float* C = (float*)Cout;
#pragma unroll
    for (int m = 0; m < 8; ++m)
#pragma unroll
      for (int n = 0; n < 4; ++n)
#pragma unroll
        for (int r = 0; r < 4; ++r)
          C[(arow0 + wm * 128 + m * 16 + klo * 4 + r) * 1024 + bcol0 + wn * 64 + n * 16 + frow] =
              acc[m][n][r];
  } else {
    // ---------------- epilogue: fused attention (wave-private) ----------------
    ushort_t* W = &lds[wid * 4096];  // [64][64] bf16, granule ^= fsw(row)
    ushort_t* out1 = (ushort_t*)Cout;
    const int head = nblk * 4 + wn;
    const int bbatch = mblk >> 4;
    const size_t kvbase = ((size_t)bbatch * H_ + head) * (size_t)(S_ * DH_);
    bfrag kb[4][2], vb[4][2];
#pragma unroll
    for (int nf = 0; nf < 4; ++nf)
#pragma unroll
      for (int kk = 0; kk < 2; ++kk) {
        kb[nf][kk] = *(const bfrag*)&kbuf[kvbase + (nf * 16 + frow) * 64 + kk * 32 + klo * 8];
        vb[nf][kk] = *(const bfrag*)&vbuf[kvbase + (nf * 16 + frow) * 64 + kk * 32 + klo * 8];
      }
#pragma unroll
    for (int hh = 0; hh < 2; ++hh) {
      // q -> W (bf16, swizzled)
#pragma unroll
      for (int m2 = 0; m2 < 4; ++m2)
#pragma unroll
        for (int r = 0; r < 4; ++r) {
          const int row = m2 * 16 + klo * 4 + r;
          const int fs = fsw(row);
#pragma unroll
          for (int n = 0; n < 4; ++n) {
            const int cc = n * 16 + frow;
            W[row * 64 + ((((cc >> 3) ^ fs) << 3) | (cc & 7))] = f2bf(acc[hh * 4 + m2][n][r]);
          }
        }
      // sim = q @ K^T
      f32x4 s[4][4] = {};
#pragma unroll
      for (int m2 = 0; m2 < 4; ++m2) {
        const int row = m2 * 16 + frow;
        const int fs = fsw(row);
#pragma unroll
        for (int kk = 0; kk < 2; ++kk) {
          bfrag qa = *(const bfrag*)&W[row * 64 + (((kk * 4 + klo) ^ fs) << 3)];
#pragma unroll
          for (int nf = 0; nf < 4; ++nf)
            s[m2][nf] = mfma16x16x32(qa, kb[nf][kk], s[m2][nf]);
        }
      }
      // softmax over 64 keys (row in one 16-lane group, 4 keys/lane/frag)
#pragma unroll
      for (int m2 = 0; m2 < 4; ++m2)
#pragma unroll
        for (int r = 0; r < 4; ++r) {
          float a0 = s[m2][0][r], a1 = s[m2][1][r], a2 = s[m2][2][r], a3 = s[m2][3][r];
          float mx = fmaxf(fmaxf(a0, a1), fmaxf(a2, a3));
#pragma unroll
          for (int o = 1; o < 16; o <<= 1) mx = fmaxf(mx, __shfl_xor(mx, o));
          a0 = __expf(a0 - mx); a1 = __expf(a1 - mx);
          a2 = __expf(a2 - mx); a3 = __expf(a3 - mx);
          float sm = (a0 + a1) + (a2 + a3);
#pragma unroll
          for (int o = 1; o < 16; o <<= 1) sm += __shfl_xor(sm, o);
          const float inv = 1.0f / sm;
          s[m2][0][r] = a0 * inv; s[m2][1][r] = a1 * inv;
          s[m2][2][r] = a2 * inv; s[m2][3][r] = a3 * inv;
        }
      // P -> W (overwrite q; wave-private, in-order LDS)
#pragma unroll
      for (int m2 = 0; m2 < 4; ++m2)
#pragma unroll
        for (int r = 0; r < 4; ++r) {
          const int row = m2 * 16 + klo * 4 + r;
          const int fs = fsw(row);
#pragma unroll
          for (int n = 0; n < 4; ++n) {
            const int cc = n * 16 + frow;
            W[row * 64 + ((((cc >> 3) ^ fs) << 3) | (cc & 7))] = f2bf(s[m2][n][r]);
          }
        }
      // out1_half = attn @ "V^T" (einsum quirk: contract attn-keys with V dims)
      f32x4 o[4][4] = {};
#pragma unroll
      for (int m2 = 0; m2 < 4; ++m2) {
        const int row = m2 * 16 + frow;
        const int fs = fsw(row);
#pragma unroll
        for (int kk = 0; kk < 2; ++kk) {
          bfrag pa = *(const bfrag*)&W[row * 64 + (((kk * 4 + klo) ^ fs) << 3)];
#pragma unroll
          for (int nf = 0; nf < 4; ++nf)
            o[m2][nf] = mfma16x16x32(pa, vb[nf][kk], o[m2][nf]);
        }
      }
      // o -> W then coalesced uint4 stores
#pragma unroll
      for (int m2 = 0; m2 < 4; ++m2)
#pragma unroll
        for (int r = 0; r < 4; ++r) {
          const int row = m2 * 16 + klo * 4 + r;
          const int fs = fsw(row);
#pragma unroll
          for (int n = 0; n < 4; ++n) {
            const int cc = n * 16 + frow;
            W[row * 64 + ((((cc >> 3) ^ fs) << 3) | (cc & 7))] = f2bf(o[m2][n][r]);
          }
        }
      const size_t grow0 = arow0 + wm * 128 + hh * 64;
#pragma unroll
      for (int it = 0; it < 8; ++it) {
        const int idx = it * 64 + lane;
        const int rr = idx >> 3, gs = idx & 7;
        const int gcol = (gs ^ fsw(rr)) << 3;
        *(uint4*)&out1[(grow0 + rr) * 1024 + head * 64 + gcol] =
            *(const uint4*)&W[rr * 64 + gs * 8];
      }
    }
  }
}

// -------------------------------- launch --------------------------------
extern "C" void kernel_launch(void* const* d_in, const int* in_sizes, int n_in,
                              void* d_out, int out_size, void* d_ws, size_t ws_size,
                              hipStream_t stream) {
  const float* x = (const float*)d_in[0];
  const float* lat = (const float*)d_in[1];
  const float* lxg = (const float*)d_in[2];
  const float* lxb = (const float*)d_in[3];
  const float* llg = (const float*)d_in[4];
  const float* llb = (const float*)d_in[5];
  const float* Wq = (const float*)d_in[6];
  const float* Wkv = (const float*)d_in[7];
  const float* Wout = (const float*)d_in[8];
  float* out = (float*)d_out;
  char* ws = (char*)d_ws;

  // ws layout (142MB): xn 2MB | wqT 2MB | wkvT 4MB | woT 2MB | k 2MB | v 2MB | out1 128MB
  ushort_t* xn = (ushort_t*)(ws);
  ushort_t* wqT = (ushort_t*)(ws + (2ull << 20));
  ushort_t* wkvT = (ushort_t*)(ws + (4ull << 20));
  ushort_t* woT = (ushort_t*)(ws + (8ull << 20));
  ushort_t* kbuf = (ushort_t*)(ws + (10ull << 20));
  ushort_t* vbuf = (ushort_t*)(ws + (12ull << 20));
  ushort_t* out1 = (ushort_t*)(ws + (14ull << 20));
  // lnl (bf16, 128MB) lives in d_out's first half: dead before final GEMM writes d_out
  ushort_t* lnl = (ushort_t*)d_out;

  dim3 tb(32, 8);
  transpose_cast_kernel<<<dim3(1024 / 32, 32), tb, 0, stream>>>(Wq, wqT, 1024, 0.125f);
  transpose_cast_kernel<<<dim3(2048 / 32, 32), tb, 0, stream>>>(Wkv, wkvT, 2048, 1.0f);
  transpose_cast_kernel<<<dim3(1024 / 32, 32), tb, 0, stream>>>(Wout, woT, 1024, 1.0f);
  ln_rows_kernel<<<B_ * S_ / 4, 256, 0, stream>>>(x, lxg, lxb, xn);
  ln_rows_kernel<<<B_ * M_ / 4, 256, 0, stream>>>(lat, llg, llb, lnl);
  gemm_kv_kernel<<<dim3(8, 16), 256, 0, stream>>>(xn, wkvT, kbuf, vbuf);
  gemm256_kernel<1><<<1024, 512, 0, stream>>>(lnl, wqT, kbuf, vbuf, out1);
  gemm256_kernel<0><<<1024, 512, 0, stream>>>(out1, woT, nullptr, nullptr, out);
}